// Round 3
// baseline (1609.747 us; speedup 1.0000x reference)
//
#include <hip/hip_runtime.h>
#include <hip/hip_bf16.h>

// Problem constants (GraphPFN layer)
constexpr int D   = 192;
constexpr float COEF = 0.14433756729740643f; // 1/sqrt(48)

__device__ __forceinline__ float gelu_f(float v) {
    return 0.5f * v * (1.0f + erff(v * 0.7071067811865475f));
}

__device__ __forceinline__ float bf2f(unsigned short u) {
    unsigned x = ((unsigned)u) << 16;
    union { unsigned u; float f; } c; c.u = x; return c.f;
}
__device__ __forceinline__ unsigned short f2bf(float f) {
    __hip_bfloat16 h = __float2bfloat16(f);
    union { __hip_bfloat16 h; unsigned short s; } c; c.h = h; return c.s;
}

// vector loaders: 4 consecutive elements -> float4
__device__ __forceinline__ float4 load4(const float* p) { return *(const float4*)p; }
__device__ __forceinline__ float4 load4(const unsigned short* p) {
    uint2 u = *(const uint2*)p;
    float4 r;
    r.x = bf2f((unsigned short)(u.x & 0xffff));
    r.y = bf2f((unsigned short)(u.x >> 16));
    r.z = bf2f((unsigned short)(u.y & 0xffff));
    r.w = bf2f((unsigned short)(u.y >> 16));
    return r;
}
__device__ __forceinline__ void store4(float* p, float4 v) { *(float4*)p = v; }
__device__ __forceinline__ void store4(unsigned short* p, float4 v) {
    uint2 u;
    u.x = (unsigned)f2bf(v.x) | ((unsigned)f2bf(v.y) << 16);
    u.y = (unsigned)f2bf(v.z) | ((unsigned)f2bf(v.w) << 16);
    *(uint2*)p = u;
}

// ---------------------------------------------------------------------------
// mask dtype detection: bool (1B/elem) vs int32 (4B/elem).
__global__ void detect_mask(const unsigned char* __restrict__ p, int nbytes, int* __restrict__ flag) {
    int i = blockIdx.x * blockDim.x + threadIdx.x;
    int v = 0;
    if (i < nbytes && (i & 3) != 0 && p[i] != 0) v = 1;
    unsigned long long bal = __ballot(v);
    if (bal && (threadIdx.x & 63) == 0) atomicOr(flag, 1);
}

__global__ void mask_convert(const unsigned char* __restrict__ raw, const int* __restrict__ flag,
                             int* __restrict__ mask01, int n) {
    int i = blockIdx.x * blockDim.x + threadIdx.x;
    if (i >= n) return;
    bool isBool = (flag[0] != 0);
    int m;
    if (isBool) m = (raw[i] != 0);
    else        m = (((const int*)raw)[i] != 0);
    mask01[i] = m;
}

// ---------------------------------------------------------------------------
// prefix scan over mask to build order / inv (rank permutation + its inverse)
__global__ void scan_block_sums(const int* __restrict__ m01, int* __restrict__ bsums, int n) {
    int i = blockIdx.x * 256 + threadIdx.x;
    int v = (i < n) ? m01[i] : 0;
    unsigned long long bal = __ballot(v != 0);
    __shared__ int wsum[4];
    int lane = threadIdx.x & 63, w = threadIdx.x >> 6;
    if (lane == 0) wsum[w] = __popcll(bal);
    __syncthreads();
    if (threadIdx.x == 0) bsums[blockIdx.x] = wsum[0] + wsum[1] + wsum[2] + wsum[3];
}

__global__ void scan_scan(int* __restrict__ bs, int nb) {
    // single block of 512 threads; nb <= 512
    __shared__ int s[512];
    int t = threadIdx.x;
    int v = (t < nb) ? bs[t] : 0;
    s[t] = v;
    __syncthreads();
    for (int off = 1; off < 512; off <<= 1) {
        int add = (t >= off) ? s[t - off] : 0;
        __syncthreads();
        s[t] += add;
        __syncthreads();
    }
    int incl = s[t];
    if (t < nb) bs[t] = incl - v;       // exclusive prefix
    if (t == nb - 1) bs[nb] = incl;     // total train count
}

// Reference semantics (verified on asymmetric example):
//   order_ref[i] = rank(i)   (rank = position of node i in stable train-first sort)
//   h_perm = h[order_ref]    => h_perm[p] = x[order[p]]   (gather with ORDER)
//   h_final = h_perm2[inv_order_ref], inv_order_ref = rank^{-1} = our `inv`
//   => out[j] = x[j] + attn_perm[inv[j]]
__global__ void make_order(const int* __restrict__ m01, const int* __restrict__ bs, int nb,
                           int* __restrict__ order, int* __restrict__ inv, int n) {
    int i = blockIdx.x * 256 + threadIdx.x;
    int lane = threadIdx.x & 63, w = threadIdx.x >> 6;
    int m = (i < n) ? m01[i] : 0;
    unsigned long long bal = __ballot(m != 0);
    int lower = __popcll(bal & ((1ULL << lane) - 1ULL));
    __shared__ int wsum[4];
    if (lane == 0) wsum[w] = __popcll(bal);
    __syncthreads();
    int wpre = 0;
    for (int k = 0; k < w; ++k) wpre += wsum[k];
    if (i < n) {
        int cntT = bs[blockIdx.x] + wpre + lower;   // #train in [0,i)
        int T = bs[nb];
        int o = m ? cntT : (T + (i - cntT));        // rank(i)
        order[i] = o;
        inv[o] = i;
    }
}

// ---------------------------------------------------------------------------
// gather + layernorm1: ln1[p] = LN(x[order[p]])  (one wave per row, 3 elems/lane)
__global__ __launch_bounds__(256) void gather_ln1(
    const float* __restrict__ x, const int* __restrict__ order,
    const float* __restrict__ g, const float* __restrict__ b,
    float* __restrict__ ln1, int Nn)
{
    int w = threadIdx.x >> 6, lane = threadIdx.x & 63;
    int p = blockIdx.x * 4 + w;
    if (p >= Nn) return;
    const float* xr = x + (size_t)order[p] * D;
    int c = lane * 3;
    float v0 = xr[c], v1 = xr[c + 1], v2 = xr[c + 2];
    float s = v0 + v1 + v2;
    #pragma unroll
    for (int m = 32; m; m >>= 1) s += __shfl_xor(s, m);
    float mu = s * (1.0f / 192.0f);
    float d0 = v0 - mu, d1 = v1 - mu, d2 = v2 - mu;
    float q = d0 * d0 + d1 * d1 + d2 * d2;
    #pragma unroll
    for (int m = 32; m; m >>= 1) q += __shfl_xor(q, m);
    float r = rsqrtf(q * (1.0f / 192.0f) + 1e-5f);
    ln1[(size_t)p * D + c]     = d0 * r * g[c]     + b[c];
    ln1[(size_t)p * D + c + 1] = d1 * r * g[c + 1] + b[c + 1];
    ln1[(size_t)p * D + c + 2] = d2 * r * g[c + 2] + b[c + 2];
}

// layernorm2 (no gather): in f32 -> out f32
__global__ __launch_bounds__(256) void ln2_kern(
    const float* __restrict__ in, const float* __restrict__ g, const float* __restrict__ b,
    float* __restrict__ outp, int Nn)
{
    int w = threadIdx.x >> 6, lane = threadIdx.x & 63;
    int p = blockIdx.x * 4 + w;
    if (p >= Nn) return;
    const float* xr = in + (size_t)p * D;
    int c = lane * 3;
    float v0 = xr[c], v1 = xr[c + 1], v2 = xr[c + 2];
    float s = v0 + v1 + v2;
    #pragma unroll
    for (int m = 32; m; m >>= 1) s += __shfl_xor(s, m);
    float mu = s * (1.0f / 192.0f);
    float d0 = v0 - mu, d1 = v1 - mu, d2 = v2 - mu;
    float q = d0 * d0 + d1 * d1 + d2 * d2;
    #pragma unroll
    for (int m = 32; m; m >>= 1) q += __shfl_xor(q, m);
    float r = rsqrtf(q * (1.0f / 192.0f) + 1e-5f);
    float* lr = outp + (size_t)p * D;
    lr[c]     = d0 * r * g[c]     + b[c];
    lr[c + 1] = d1 * r * g[c + 1] + b[c + 1];
    lr[c + 2] = d2 * r * g[c + 2] + b[c + 2];
}

// ---------------------------------------------------------------------------
// generic GEMM: C[M,Nc] = act(A[M,K] @ B[K,Nc] + bias) (+ residual)
// BM=BN=64, BK=16, 256 threads, 4x4 per thread. A: TA (f32/bf16), C: TC.
template<int ACT, bool RES, typename TA, typename TC>
__global__ __launch_bounds__(256) void gemm_t(
    const TA* __restrict__ A, const float* __restrict__ B,
    const float* __restrict__ bias, const float* __restrict__ Rsd,
    TC* __restrict__ C, int M, int K, int Nc)
{
    constexpr int BM = 64, BN = 64, BK = 16;
    __shared__ float As[BK][BM];
    __shared__ float Bs[BK][BN];
    int tid = threadIdx.x;
    int tx = tid & 15, ty = tid >> 4;
    int bm = blockIdx.x * BM, bn = blockIdx.y * BN;
    int aRow = tid >> 2;          // 0..63
    int aCol = (tid & 3) * 4;     // 0,4,8,12
    int bRow = tid >> 4;          // 0..15
    int bCol = (tid & 15) * 4;    // 0..60
    float acc[4][4] = {};
    for (int kk = 0; kk < K; kk += BK) {
        float4 a4 = make_float4(0.f, 0.f, 0.f, 0.f);
        int ar = bm + aRow;
        if (ar < M) a4 = load4(A + (size_t)ar * K + kk + aCol);
        As[aCol + 0][aRow] = a4.x;
        As[aCol + 1][aRow] = a4.y;
        As[aCol + 2][aRow] = a4.z;
        As[aCol + 3][aRow] = a4.w;
        float4 b4 = *(const float4*)(B + (size_t)(kk + bRow) * Nc + bn + bCol);
        *(float4*)&Bs[bRow][bCol] = b4;
        __syncthreads();
        #pragma unroll
        for (int k = 0; k < BK; ++k) {
            float4 av = *(const float4*)&As[k][ty * 4];
            float4 bv = *(const float4*)&Bs[k][tx * 4];
            float aa[4] = {av.x, av.y, av.z, av.w};
            float bb[4] = {bv.x, bv.y, bv.z, bv.w};
            #pragma unroll
            for (int i = 0; i < 4; ++i)
                #pragma unroll
                for (int j = 0; j < 4; ++j)
                    acc[i][j] += aa[i] * bb[j];
        }
        __syncthreads();
    }
    float4 bv = *(const float4*)(bias + bn + tx * 4);
    float bb[4] = {bv.x, bv.y, bv.z, bv.w};
    #pragma unroll
    for (int i = 0; i < 4; ++i) {
        int row = bm + ty * 4 + i;
        if (row >= M) break;
        float r[4];
        #pragma unroll
        for (int j = 0; j < 4; ++j) {
            float t = acc[i][j] + bb[j];
            if (ACT == 1) t = gelu_f(t);
            r[j] = t;
        }
        size_t base = (size_t)row * Nc + bn + tx * 4;
        if (RES) {
            float4 rr = *(const float4*)(Rsd + base);
            r[0] += rr.x; r[1] += rr.y; r[2] += rr.z; r[3] += rr.w;
        }
        store4(C + base, make_float4(r[0], r[1], r[2], r[3]));
    }
}

// ---------------------------------------------------------------------------
// row_start[n] = lower_bound(dst, n) for n in [0, N]
__global__ void row_starts(const int* __restrict__ dst, int* __restrict__ rowst, int Nn, int Ee) {
    int n = blockIdx.x * blockDim.x + threadIdx.x;
    if (n > Nn) return;
    int lo = 0, hi = Ee;
    while (lo < hi) {
        int mid = (lo + hi) >> 1;
        if (dst[mid] < n) lo = mid + 1; else hi = mid;
    }
    rowst[n] = lo;
}

// ---------------------------------------------------------------------------
// per-edge scores: one wave per edge (16 lanes per head).
// qkv (bf16) row layout: node*576; head h: q at h*144, k at +48, v at +96
__global__ __launch_bounds__(256) void edge_scores(
    const unsigned short* __restrict__ qkv, const int* __restrict__ src, const int* __restrict__ dst,
    float* __restrict__ score, int Ee)
{
    int w = threadIdx.x >> 6, lane = threadIdx.x & 63;
    long e = (long)blockIdx.x * 4 + w;
    if (e >= Ee) return;
    int se = src[e], de = dst[e];
    int head = lane >> 4, t = lane & 15;
    int c = t * 3;
    const unsigned short* kr = qkv + (size_t)se * 576 + head * 144 + 48 + c;
    const unsigned short* qr = qkv + (size_t)de * 576 + head * 144 + c;
    float s = bf2f(kr[0]) * bf2f(qr[0]) + bf2f(kr[1]) * bf2f(qr[1]) + bf2f(kr[2]) * bf2f(qr[2]);
    s += __shfl_xor(s, 1);
    s += __shfl_xor(s, 2);
    s += __shfl_xor(s, 4);
    s += __shfl_xor(s, 8);
    if (t == 0) score[(size_t)e * 4 + head] = s * COEF;
}

// ---------------------------------------------------------------------------
// per-node softmax + V aggregation: one wave per node
__global__ __launch_bounds__(256) void node_attn(
    const unsigned short* __restrict__ qkv, const float* __restrict__ score,
    const int* __restrict__ src, const int* __restrict__ rowst,
    float* __restrict__ agg, int Nn)
{
    int w = threadIdx.x >> 6, lane = threadIdx.x & 63;
    int n = blockIdx.x * 4 + w;
    if (n >= Nn) return;
    int r0 = rowst[n], r1 = rowst[n + 1];

    float mx0 = -3.4e38f, mx1 = -3.4e38f, mx2 = -3.4e38f, mx3 = -3.4e38f;
    for (int e = r0 + lane; e < r1; e += 64) {
        float4 sc = *(const float4*)(score + (size_t)e * 4);
        mx0 = fmaxf(mx0, sc.x); mx1 = fmaxf(mx1, sc.y);
        mx2 = fmaxf(mx2, sc.z); mx3 = fmaxf(mx3, sc.w);
    }
    #pragma unroll
    for (int m = 32; m; m >>= 1) {
        mx0 = fmaxf(mx0, __shfl_xor(mx0, m));
        mx1 = fmaxf(mx1, __shfl_xor(mx1, m));
        mx2 = fmaxf(mx2, __shfl_xor(mx2, m));
        mx3 = fmaxf(mx3, __shfl_xor(mx3, m));
    }
    float sm0 = 0.f, sm1 = 0.f, sm2 = 0.f, sm3 = 0.f;
    for (int e = r0 + lane; e < r1; e += 64) {
        float4 sc = *(const float4*)(score + (size_t)e * 4);
        sm0 += expf(sc.x - mx0); sm1 += expf(sc.y - mx1);
        sm2 += expf(sc.z - mx2); sm3 += expf(sc.w - mx3);
    }
    #pragma unroll
    for (int m = 32; m; m >>= 1) {
        sm0 += __shfl_xor(sm0, m);
        sm1 += __shfl_xor(sm1, m);
        sm2 += __shfl_xor(sm2, m);
        sm3 += __shfl_xor(sm3, m);
    }
    int head = lane >> 4;
    float mh = (head == 0) ? mx0 : (head == 1) ? mx1 : (head == 2) ? mx2 : mx3;
    float zh = (head == 0) ? sm0 : (head == 1) ? sm1 : (head == 2) ? sm2 : sm3;
    float iz = (r1 > r0) ? (1.0f / zh) : 0.0f;
    int c = (lane & 15) * 3;
    float a0 = 0.f, a1 = 0.f, a2 = 0.f;
    for (int e = r0; e < r1; ++e) {
        int se = src[e];
        float s = score[(size_t)e * 4 + head];
        float pc = expf(s - mh) * iz;
        const unsigned short* vr = qkv + (size_t)se * 576 + head * 144 + 96 + c;
        a0 += pc * bf2f(vr[0]);
        a1 += pc * bf2f(vr[1]);
        a2 += pc * bf2f(vr[2]);
    }
    float* ar = agg + (size_t)n * D + lane * 3;
    ar[0] = a0; ar[1] = a1; ar[2] = a2;
}

// ---------------------------------------------------------------------------
// out[j] = x[j] + attnout[inv[j]]  (float4 granularity: 48 per row)
__global__ void add_unperm(const float4* __restrict__ x, const float4* __restrict__ attn,
                           const int* __restrict__ inv, float4* __restrict__ outp, int Nn)
{
    long t = (long)blockIdx.x * blockDim.x + threadIdx.x;
    if (t >= (long)Nn * 48) return;
    int j = (int)(t / 48);
    int cc = (int)(t - (long)j * 48);
    float4 a = x[(size_t)j * 48 + cc];
    float4 b = attn[(size_t)inv[j] * 48 + cc];
    a.x += b.x; a.y += b.y; a.z += b.z; a.w += b.w;
    outp[(size_t)j * 48 + cc] = a;
}

// ---------------------------------------------------------------------------
extern "C" void kernel_launch(void* const* d_in, const int* in_sizes, int n_in,
                              void* d_out, int out_size, void* d_ws, size_t ws_size,
                              hipStream_t stream)
{
    const float* x            = (const float*)d_in[0];
    const unsigned char* mraw = (const unsigned char*)d_in[1];
    const int* src            = (const int*)d_in[2];
    const int* dst            = (const int*)d_in[3];
    const float* ln1_g        = (const float*)d_in[4];
    const float* ln1_b        = (const float*)d_in[5];
    const float* Wqkv         = (const float*)d_in[6];
    const float* bqkv         = (const float*)d_in[7];
    const float* Wout         = (const float*)d_in[8];
    const float* bout         = (const float*)d_in[9];
    const float* ln2_g        = (const float*)d_in[10];
    const float* ln2_b        = (const float*)d_in[11];
    const float* W1           = (const float*)d_in[12];
    const float* b1           = (const float*)d_in[13];
    const float* W2           = (const float*)d_in[14];
    const float* b2           = (const float*)d_in[15];
    float* out = (float*)d_out;

    const int Nn = in_sizes[1];   // 100000 nodes
    const int Ee = in_sizes[2];   // 1600000 edges
    const int nb = (Nn + 255) / 256;

    // workspace carve (aligned 256B). Total ≈ 220 MB.
    char* wsp = (char*)d_ws;
    size_t off = 0;
    auto alloc = [&](size_t bytes) -> void* {
        void* p = wsp + off;
        off = (off + bytes + 255) & ~(size_t)255;
        return p;
    };
    int*   flag   = (int*)alloc(sizeof(int));
    int*   bsums  = (int*)alloc((size_t)(nb + 1) * sizeof(int));
    int*   mask01 = (int*)alloc((size_t)Nn * sizeof(int));
    int*   order  = (int*)alloc((size_t)Nn * sizeof(int));
    int*   inv    = (int*)alloc((size_t)Nn * sizeof(int));
    int*   rowst  = (int*)alloc((size_t)(Nn + 1) * sizeof(int));
    // B1: ln1 -> agg -> hn (f32, Nn*192)
    float* B1     = (float*)alloc((size_t)Nn * D * sizeof(float));
    // B2: qkv bf16 (Nn*576*2B) -> attnout f32 (Nn*192*4B) -> g1 bf16 (Nn*384*2B)
    void*  B2     = alloc((size_t)Nn * 576 * sizeof(unsigned short));
    // B3: scores (Ee*4 f32)
    float* B3     = (float*)alloc((size_t)Ee * 4 * sizeof(float));
    (void)ws_size; (void)n_in; (void)out_size;

    unsigned short* qkvb   = (unsigned short*)B2;
    float*          attnb  = (float*)B2;
    unsigned short* g1b    = (unsigned short*)B2;

    hipMemsetAsync(flag, 0, sizeof(int), stream);
    hipLaunchKernelGGL(detect_mask, dim3(nb), dim3(256), 0, stream, mraw, Nn, flag);
    hipLaunchKernelGGL(mask_convert, dim3(nb), dim3(256), 0, stream, mraw, flag, mask01, Nn);
    hipLaunchKernelGGL(scan_block_sums, dim3(nb), dim3(256), 0, stream, mask01, bsums, Nn);
    hipLaunchKernelGGL(scan_scan, dim3(1), dim3(512), 0, stream, bsums, nb);
    hipLaunchKernelGGL(make_order, dim3(nb), dim3(256), 0, stream, mask01, bsums, nb, order, inv, Nn);

    // ln1[p] = LN(x[order[p]])   (gather with ORDER — matches h[order] in reference)
    hipLaunchKernelGGL(gather_ln1, dim3((Nn + 3) / 4), dim3(256), 0, stream,
                       x, order, ln1_g, ln1_b, B1, Nn);

    // qkv(bf16) = ln1 @ Wqkv + bqkv
    {
        dim3 g((Nn + 63) / 64, 576 / 64);
        hipLaunchKernelGGL((gemm_t<0, false, float, unsigned short>), g, dim3(256), 0, stream,
                           B1, Wqkv, bqkv, (const float*)nullptr, qkvb, Nn, 192, 576);
    }

    hipLaunchKernelGGL(row_starts, dim3((Nn + 1 + 255) / 256), dim3(256), 0, stream, dst, rowst, Nn, Ee);
    hipLaunchKernelGGL(edge_scores, dim3((Ee + 3) / 4), dim3(256), 0, stream, qkvb, src, dst, B3, Ee);
    hipLaunchKernelGGL(node_attn, dim3((Nn + 3) / 4), dim3(256), 0, stream, qkvb, B3, src, rowst, B1, Nn);

    // attnout(f32) = agg @ Wout + bout   (B1 -> B2; qkv dead)
    {
        dim3 g((Nn + 63) / 64, 192 / 64);
        hipLaunchKernelGGL((gemm_t<0, false, float, float>), g, dim3(256), 0, stream,
                           B1, Wout, bout, (const float*)nullptr, attnb, Nn, 192, 192);
    }

    // out[j] = x[j] + attnout[inv[j]]
    hipLaunchKernelGGL(add_unperm, dim3((unsigned)(((long)Nn * 48 + 255) / 256)), dim3(256), 0, stream,
                       (const float4*)x, (const float4*)attnb, inv, (float4*)out, Nn);

    // hn = LN2(out) into B1 (agg dead)
    hipLaunchKernelGGL(ln2_kern, dim3((Nn + 3) / 4), dim3(256), 0, stream, out, ln2_g, ln2_b, B1, Nn);

    // g1(bf16) = gelu(hn @ W1 + b1) into B2 (attnout dead)
    {
        dim3 g((Nn + 63) / 64, 384 / 64);
        hipLaunchKernelGGL((gemm_t<1, false, float, unsigned short>), g, dim3(256), 0, stream,
                           B1, W1, b1, (const float*)nullptr, g1b, Nn, 192, 384);
    }
    // out = out + g1 @ W2 + b2
    {
        dim3 g((Nn + 63) / 64, 192 / 64);
        hipLaunchKernelGGL((gemm_t<0, true, unsigned short, float>), g, dim3(256), 0, stream,
                           g1b, W2, b2, out, out, Nn, 384, 192);
    }
}

// Round 6
// 1117.022 us; speedup vs baseline: 1.4411x; 1.4411x over previous
//
#include <hip/hip_runtime.h>
#include <hip/hip_bf16.h>

constexpr int D   = 192;
constexpr float COEF = 0.14433756729740643f; // 1/sqrt(48)

typedef unsigned short u16;
typedef __bf16 bf16x8 __attribute__((ext_vector_type(8)));
typedef float  f32x4  __attribute__((ext_vector_type(4)));

__device__ __forceinline__ float gelu_f(float v) {
    return 0.5f * v * (1.0f + erff(v * 0.7071067811865475f));
}
__device__ __forceinline__ float bf2f(u16 u) {
    unsigned x = ((unsigned)u) << 16;
    union { unsigned u; float f; } c; c.u = x; return c.f;
}
__device__ __forceinline__ u16 f2bf(float f) {
    __hip_bfloat16 h = __float2bfloat16(f);
    union { __hip_bfloat16 h; u16 s; } c; c.h = h; return c.s;
}
// split f32 -> hi/lo bf16 pair (v ~= hi + lo, residual ~2^-18 rel)
__device__ __forceinline__ void splitbf(float v, u16& hi, u16& lo) {
    hi = f2bf(v);
    lo = f2bf(v - bf2f(hi));
}

// ---------------------------------------------------------------------------
// mask dtype detection: bool (1B) vs int32 (4B)
__global__ void detect_mask(const unsigned char* __restrict__ p, int nbytes, int* __restrict__ flag) {
    int i = blockIdx.x * blockDim.x + threadIdx.x;
    int v = 0;
    if (i < nbytes && (i & 3) != 0 && p[i] != 0) v = 1;
    unsigned long long bal = __ballot(v);
    if (bal && (threadIdx.x & 63) == 0) atomicOr(flag, 1);
}
__global__ void mask_convert(const unsigned char* __restrict__ raw, const int* __restrict__ flag,
                             int* __restrict__ mask01, int n) {
    int i = blockIdx.x * blockDim.x + threadIdx.x;
    if (i >= n) return;
    bool isBool = (flag[0] != 0);
    mask01[i] = isBool ? (raw[i] != 0) : (((const int*)raw)[i] != 0);
}

// ---------------------------------------------------------------------------
// prefix scan over mask to build order / inv (rank permutation + inverse)
__global__ void scan_block_sums(const int* __restrict__ m01, int* __restrict__ bsums, int n) {
    int i = blockIdx.x * 256 + threadIdx.x;
    int v = (i < n) ? m01[i] : 0;
    unsigned long long bal = __ballot(v != 0);
    __shared__ int wsum[4];
    int lane = threadIdx.x & 63, w = threadIdx.x >> 6;
    if (lane == 0) wsum[w] = __popcll(bal);
    __syncthreads();
    if (threadIdx.x == 0) bsums[blockIdx.x] = wsum[0] + wsum[1] + wsum[2] + wsum[3];
}
__global__ void scan_scan(int* __restrict__ bs, int nb) {
    __shared__ int s[512];
    int t = threadIdx.x;
    int v = (t < nb) ? bs[t] : 0;
    s[t] = v;
    __syncthreads();
    for (int off = 1; off < 512; off <<= 1) {
        int add = (t >= off) ? s[t - off] : 0;
        __syncthreads();
        s[t] += add;
        __syncthreads();
    }
    int incl = s[t];
    if (t < nb) bs[t] = incl - v;
    if (t == nb - 1) bs[nb] = incl;
}
__global__ void make_order(const int* __restrict__ m01, const int* __restrict__ bs, int nb,
                           int* __restrict__ order, int* __restrict__ inv, int n) {
    int i = blockIdx.x * 256 + threadIdx.x;
    int lane = threadIdx.x & 63, w = threadIdx.x >> 6;
    int m = (i < n) ? m01[i] : 0;
    unsigned long long bal = __ballot(m != 0);
    int lower = __popcll(bal & ((1ULL << lane) - 1ULL));
    __shared__ int wsum[4];
    if (lane == 0) wsum[w] = __popcll(bal);
    __syncthreads();
    int wpre = 0;
    for (int k = 0; k < w; ++k) wpre += wsum[k];
    if (i < n) {
        int cntT = bs[blockIdx.x] + wpre + lower;
        int T = bs[nb];
        int o = m ? cntT : (T + (i - cntT));  // rank(i)
        order[i] = o;
        inv[o] = i;
    }
}

// ---------------------------------------------------------------------------
// weight convert+transpose into hi/lo: Wt*[n*K+k] = split(W[k*N+n])
__global__ void wt_kern(const float* __restrict__ W, u16* __restrict__ Wth, u16* __restrict__ Wtl,
                        int K, int N) {
    int i = blockIdx.x * blockDim.x + threadIdx.x;
    if (i >= K * N) return;
    int k = i / N, n = i - k * N;
    u16 h, l;
    splitbf(W[i], h, l);
    Wth[(size_t)n * K + k] = h;
    Wtl[(size_t)n * K + k] = l;
}

// ---------------------------------------------------------------------------
// gather + LN1 -> hi/lo bf16
__global__ __launch_bounds__(256) void gather_ln1(
    const float* __restrict__ x, const int* __restrict__ order,
    const float* __restrict__ g, const float* __restrict__ b,
    u16* __restrict__ lnH, u16* __restrict__ lnL, int Nn)
{
    int w = threadIdx.x >> 6, lane = threadIdx.x & 63;
    int p = blockIdx.x * 4 + w;
    if (p >= Nn) return;
    const float* xr = x + (size_t)order[p] * D;
    int c = lane * 3;
    float v0 = xr[c], v1 = xr[c + 1], v2 = xr[c + 2];
    float s = v0 + v1 + v2;
    #pragma unroll
    for (int m = 32; m; m >>= 1) s += __shfl_xor(s, m);
    float mu = s * (1.0f / 192.0f);
    float d0 = v0 - mu, d1 = v1 - mu, d2 = v2 - mu;
    float q = d0 * d0 + d1 * d1 + d2 * d2;
    #pragma unroll
    for (int m = 32; m; m >>= 1) q += __shfl_xor(q, m);
    float r = rsqrtf(q * (1.0f / 192.0f) + 1e-5f);
    float o0 = d0 * r * g[c]     + b[c];
    float o1 = d1 * r * g[c + 1] + b[c + 1];
    float o2 = d2 * r * g[c + 2] + b[c + 2];
    size_t base = (size_t)p * D + c;
    u16 h, l;
    splitbf(o0, h, l); lnH[base] = h;     lnL[base] = l;
    splitbf(o1, h, l); lnH[base + 1] = h; lnL[base + 1] = l;
    splitbf(o2, h, l); lnH[base + 2] = h; lnL[base + 2] = l;
}

// LN2: f32 in -> hi/lo bf16 out
__global__ __launch_bounds__(256) void ln2_kern(
    const float* __restrict__ in, const float* __restrict__ g, const float* __restrict__ b,
    u16* __restrict__ outH, u16* __restrict__ outL, int Nn)
{
    int w = threadIdx.x >> 6, lane = threadIdx.x & 63;
    int p = blockIdx.x * 4 + w;
    if (p >= Nn) return;
    const float* xr = in + (size_t)p * D;
    int c = lane * 3;
    float v0 = xr[c], v1 = xr[c + 1], v2 = xr[c + 2];
    float s = v0 + v1 + v2;
    #pragma unroll
    for (int m = 32; m; m >>= 1) s += __shfl_xor(s, m);
    float mu = s * (1.0f / 192.0f);
    float d0 = v0 - mu, d1 = v1 - mu, d2 = v2 - mu;
    float q = d0 * d0 + d1 * d1 + d2 * d2;
    #pragma unroll
    for (int m = 32; m; m >>= 1) q += __shfl_xor(q, m);
    float r = rsqrtf(q * (1.0f / 192.0f) + 1e-5f);
    float o0 = d0 * r * g[c]     + b[c];
    float o1 = d1 * r * g[c + 1] + b[c + 1];
    float o2 = d2 * r * g[c + 2] + b[c + 2];
    size_t base = (size_t)p * D + c;
    u16 h, l;
    splitbf(o0, h, l); outH[base] = h;     outL[base] = l;
    splitbf(o1, h, l); outH[base + 1] = h; outL[base + 1] = l;
    splitbf(o2, h, l); outH[base + 2] = h; outL[base + 2] = l;
}

// ---------------------------------------------------------------------------
// Split-precision MFMA GEMM: C = A[M,K] @ B[K,Nc] + bias.
// A given as hi(+lo) bf16, Bt as hi+lo bf16 [Nc][K].
// A*B ~= Ah*Bh + Ah*Bl (+ Al*Bh if SPLITA) — f32-grade accuracy.
// BM=BN=64, BK=32, 4 waves (2x2), each wave 2x2 frags of 16x16x32.
// EPI: 0 = route cols to q/k/v bf16 buffers (Nc=576)
//      1 = out[perm[row]] = x[perm[row]] + val   (scatter with ORDER: inv[order[p]]=p
//          so out[j]=attn[inv[j]] <=> writing row p to j=order[p])
//      2 = obf[row] = bf16(gelu(val))
//      3 = outF[row] += val                      (f32 RMW residual)
template<int EPI, bool SPLITA>
__global__ __launch_bounds__(256) void gemm_mfma(
    const u16* __restrict__ Ah, const u16* __restrict__ Al,
    const u16* __restrict__ Bth, const u16* __restrict__ Btl,
    const float* __restrict__ bias,
    float* __restrict__ outF, const float* __restrict__ xres, const int* __restrict__ perm,
    u16* __restrict__ oq, u16* __restrict__ ok, u16* __restrict__ ov, u16* __restrict__ obf,
    int M, int K, int Nc)
{
    constexpr int LDT = 40;               // padded LDS row: only 2-way bank conflicts (free)
    __shared__ u16 AsH[64 * LDT];
    __shared__ u16 AsL[64 * LDT];
    __shared__ u16 BsH[64 * LDT];
    __shared__ u16 BsL[64 * LDT];
    int tid = threadIdx.x;
    int lane = tid & 63, w = tid >> 6;
    int wr = w >> 1, wc = w & 1;
    int bm = blockIdx.x * 64, bn = blockIdx.y * 64;

    int srow = tid >> 2;                  // 0..63
    int scg  = (tid & 3) * 8;             // 0,8,16,24

    f32x4 acc[2][2];
    #pragma unroll
    for (int i = 0; i < 2; ++i)
        #pragma unroll
        for (int j = 0; j < 2; ++j)
            acc[i][j] = (f32x4){0.f, 0.f, 0.f, 0.f};

    for (int kk = 0; kk < K; kk += 32) {
        bool arow_ok = (bm + srow < M);
        size_t aoff = (size_t)(bm + srow) * K + kk + scg;
        uint4 avh = make_uint4(0, 0, 0, 0);
        if (arow_ok) avh = *(const uint4*)(Ah + aoff);
        *(uint4*)&AsH[srow * LDT + scg] = avh;
        if (SPLITA) {
            uint4 avl = make_uint4(0, 0, 0, 0);
            if (arow_ok) avl = *(const uint4*)(Al + aoff);
            *(uint4*)&AsL[srow * LDT + scg] = avl;
        }
        size_t boff = (size_t)(bn + srow) * K + kk + scg;
        *(uint4*)&BsH[srow * LDT + scg] = *(const uint4*)(Bth + boff);
        *(uint4*)&BsL[srow * LDT + scg] = *(const uint4*)(Btl + boff);
        __syncthreads();

        int arow = (wr * 32 + (lane & 15)) * LDT + (lane >> 4) * 8;
        int brow = (wc * 32 + (lane & 15)) * LDT + (lane >> 4) * 8;
        bf16x8 a0h = *(const bf16x8*)&AsH[arow];
        bf16x8 a1h = *(const bf16x8*)&AsH[arow + 16 * LDT];
        bf16x8 b0h = *(const bf16x8*)&BsH[brow];
        bf16x8 b1h = *(const bf16x8*)&BsH[brow + 16 * LDT];
        bf16x8 b0l = *(const bf16x8*)&BsL[brow];
        bf16x8 b1l = *(const bf16x8*)&BsL[brow + 16 * LDT];
        acc[0][0] = __builtin_amdgcn_mfma_f32_16x16x32_bf16(a0h, b0h, acc[0][0], 0, 0, 0);
        acc[0][1] = __builtin_amdgcn_mfma_f32_16x16x32_bf16(a0h, b1h, acc[0][1], 0, 0, 0);
        acc[1][0] = __builtin_amdgcn_mfma_f32_16x16x32_bf16(a1h, b0h, acc[1][0], 0, 0, 0);
        acc[1][1] = __builtin_amdgcn_mfma_f32_16x16x32_bf16(a1h, b1h, acc[1][1], 0, 0, 0);
        acc[0][0] = __builtin_amdgcn_mfma_f32_16x16x32_bf16(a0h, b0l, acc[0][0], 0, 0, 0);
        acc[0][1] = __builtin_amdgcn_mfma_f32_16x16x32_bf16(a0h, b1l, acc[0][1], 0, 0, 0);
        acc[1][0] = __builtin_amdgcn_mfma_f32_16x16x32_bf16(a1h, b0l, acc[1][0], 0, 0, 0);
        acc[1][1] = __builtin_amdgcn_mfma_f32_16x16x32_bf16(a1h, b1l, acc[1][1], 0, 0, 0);
        if (SPLITA) {
            bf16x8 a0l = *(const bf16x8*)&AsL[arow];
            bf16x8 a1l = *(const bf16x8*)&AsL[arow + 16 * LDT];
            acc[0][0] = __builtin_amdgcn_mfma_f32_16x16x32_bf16(a0l, b0h, acc[0][0], 0, 0, 0);
            acc[0][1] = __builtin_amdgcn_mfma_f32_16x16x32_bf16(a0l, b1h, acc[0][1], 0, 0, 0);
            acc[1][0] = __builtin_amdgcn_mfma_f32_16x16x32_bf16(a1l, b0h, acc[1][0], 0, 0, 0);
            acc[1][1] = __builtin_amdgcn_mfma_f32_16x16x32_bf16(a1l, b1h, acc[1][1], 0, 0, 0);
        }
        __syncthreads();
    }

    // C/D layout: col = lane&15, row = (lane>>4)*4 + reg  [m89 verified]
    #pragma unroll
    for (int fm = 0; fm < 2; ++fm) {
        #pragma unroll
        for (int fn = 0; fn < 2; ++fn) {
            int col = bn + wc * 32 + fn * 16 + (lane & 15);
            float bcol = bias[col];
            #pragma unroll
            for (int r = 0; r < 4; ++r) {
                int row = bm + wr * 32 + fm * 16 + (lane >> 4) * 4 + r;
                if (row >= M) continue;
                float val = acc[fm][fn][r] + bcol;
                if (EPI == 0) {
                    int h = col / 144, rr = col - h * 144;
                    int sub = rr / 48, d = rr - sub * 48;
                    u16* dp = (sub == 0) ? oq : (sub == 1) ? ok : ov;
                    dp[(size_t)row * 192 + h * 48 + d] = f2bf(val);
                } else if (EPI == 1) {
                    int j = perm[row];                    // j = order[p]  (inv[j] == p)
                    size_t o = (size_t)j * Nc + col;
                    outF[o] = xres[o] + val;
                } else if (EPI == 2) {
                    obf[(size_t)row * Nc + col] = f2bf(gelu_f(val));
                } else {
                    size_t o = (size_t)row * Nc + col;
                    outF[o] += val;
                }
            }
        }
    }
}

// ---------------------------------------------------------------------------
// row_start[n] = lower_bound(dst, n)
__global__ void row_starts(const int* __restrict__ dst, int* __restrict__ rowst, int Nn, int Ee) {
    int n = blockIdx.x * blockDim.x + threadIdx.x;
    if (n > Nn) return;
    int lo = 0, hi = Ee;
    while (lo < hi) {
        int mid = (lo + hi) >> 1;
        if (dst[mid] < n) lo = mid + 1; else hi = mid;
    }
    rowst[n] = lo;
}

// ---------------------------------------------------------------------------
// per-edge scores: one wave per edge; k,q contiguous [N][192] bf16 (h*48+d)
__global__ __launch_bounds__(256) void edge_scores(
    const u16* __restrict__ kb, const u16* __restrict__ qb,
    const int* __restrict__ src, const int* __restrict__ dst,
    float* __restrict__ score, int Ee)
{
    int w = threadIdx.x >> 6, lane = threadIdx.x & 63;
    long e = (long)blockIdx.x * 4 + w;
    if (e >= Ee) return;
    int se = src[e], de = dst[e];
    int head = lane >> 4, t = lane & 15;
    int c = head * 48 + t * 3;
    const u16* kr = kb + (size_t)se * 192 + c;
    const u16* qr = qb + (size_t)de * 192 + c;
    float s = bf2f(kr[0]) * bf2f(qr[0]) + bf2f(kr[1]) * bf2f(qr[1]) + bf2f(kr[2]) * bf2f(qr[2]);
    s += __shfl_xor(s, 1);
    s += __shfl_xor(s, 2);
    s += __shfl_xor(s, 4);
    s += __shfl_xor(s, 8);
    if (t == 0) score[(size_t)e * 4 + head] = s * COEF;
}

// ---------------------------------------------------------------------------
// per-node softmax + V aggregation: one wave per node, 4-way edge parallel.
// lane = eg*16 + t; lane t owns elems [12t,12t+12) => head = t>>2.
// agg written as hi/lo bf16 (A-operand of the Wout GEMM).
__global__ __launch_bounds__(256) void node_attn(
    const u16* __restrict__ vb, const float* __restrict__ score,
    const int* __restrict__ src, const int* __restrict__ rowst,
    u16* __restrict__ aggH, u16* __restrict__ aggL, int Nn)
{
    int w = threadIdx.x >> 6, lane = threadIdx.x & 63;
    int n = blockIdx.x * 4 + w;
    if (n >= Nn) return;
    int r0 = rowst[n], r1 = rowst[n + 1];
    int eg = lane >> 4, t = lane & 15;
    int ht = t >> 2;

    float mx0 = -3.4e38f, mx1 = -3.4e38f, mx2 = -3.4e38f, mx3 = -3.4e38f;
    for (int e = r0 + lane; e < r1; e += 64) {
        float4 sc = *(const float4*)(score + (size_t)e * 4);
        mx0 = fmaxf(mx0, sc.x); mx1 = fmaxf(mx1, sc.y);
        mx2 = fmaxf(mx2, sc.z); mx3 = fmaxf(mx3, sc.w);
    }
    #pragma unroll
    for (int m = 32; m; m >>= 1) {
        mx0 = fmaxf(mx0, __shfl_xor(mx0, m));
        mx1 = fmaxf(mx1, __shfl_xor(mx1, m));
        mx2 = fmaxf(mx2, __shfl_xor(mx2, m));
        mx3 = fmaxf(mx3, __shfl_xor(mx3, m));
    }
    float sm0 = 0.f, sm1 = 0.f, sm2 = 0.f, sm3 = 0.f;
    for (int e = r0 + lane; e < r1; e += 64) {
        float4 sc = *(const float4*)(score + (size_t)e * 4);
        sm0 += expf(sc.x - mx0); sm1 += expf(sc.y - mx1);
        sm2 += expf(sc.z - mx2); sm3 += expf(sc.w - mx3);
    }
    #pragma unroll
    for (int m = 32; m; m >>= 1) {
        sm0 += __shfl_xor(sm0, m);
        sm1 += __shfl_xor(sm1, m);
        sm2 += __shfl_xor(sm2, m);
        sm3 += __shfl_xor(sm3, m);
    }
    float mh = (ht == 0) ? mx0 : (ht == 1) ? mx1 : (ht == 2) ? mx2 : mx3;
    float zh = (ht == 0) ? sm0 : (ht == 1) ? sm1 : (ht == 2) ? sm2 : sm3;
    float iz = (r1 > r0) ? (1.0f / zh) : 0.0f;

    float acc[12];
    #pragma unroll
    for (int i = 0; i < 12; ++i) acc[i] = 0.f;
    for (int e = r0 + eg; e < r1; e += 4) {
        float4 sc = *(const float4*)(score + (size_t)e * 4);
        float sh = (ht == 0) ? sc.x : (ht == 1) ? sc.y : (ht == 2) ? sc.z : sc.w;
        float p = expf(sh - mh) * iz;
        const u16* vr = vb + (size_t)src[e] * 192 + t * 12;
        ushort4 v0 = *(const ushort4*)(vr);
        ushort4 v1 = *(const ushort4*)(vr + 4);
        ushort4 v2 = *(const ushort4*)(vr + 8);
        acc[0] += p * bf2f(v0.x); acc[1]  += p * bf2f(v0.y);
        acc[2] += p * bf2f(v0.z); acc[3]  += p * bf2f(v0.w);
        acc[4] += p * bf2f(v1.x); acc[5]  += p * bf2f(v1.y);
        acc[6] += p * bf2f(v1.z); acc[7]  += p * bf2f(v1.w);
        acc[8] += p * bf2f(v2.x); acc[9]  += p * bf2f(v2.y);
        acc[10] += p * bf2f(v2.z); acc[11] += p * bf2f(v2.w);
    }
    #pragma unroll
    for (int i = 0; i < 12; ++i) {
        acc[i] += __shfl_xor(acc[i], 16);
        acc[i] += __shfl_xor(acc[i], 32);
    }
    if (eg == 0) {
        size_t base = (size_t)n * 192 + t * 12;
        #pragma unroll
        for (int i = 0; i < 12; ++i) {
            u16 h, l;
            splitbf(acc[i], h, l);
            aggH[base + i] = h;
            aggL[base + i] = l;
        }
    }
}

// ---------------------------------------------------------------------------
extern "C" void kernel_launch(void* const* d_in, const int* in_sizes, int n_in,
                              void* d_out, int out_size, void* d_ws, size_t ws_size,
                              hipStream_t stream)
{
    const float* x            = (const float*)d_in[0];
    const unsigned char* mraw = (const unsigned char*)d_in[1];
    const int* src            = (const int*)d_in[2];
    const int* dst            = (const int*)d_in[3];
    const float* ln1_g        = (const float*)d_in[4];
    const float* ln1_b        = (const float*)d_in[5];
    const float* Wqkv         = (const float*)d_in[6];
    const float* bqkv         = (const float*)d_in[7];
    const float* Wout         = (const float*)d_in[8];
    const float* bout         = (const float*)d_in[9];
    const float* ln2_g        = (const float*)d_in[10];
    const float* ln2_b        = (const float*)d_in[11];
    const float* W1           = (const float*)d_in[12];
    const float* b1           = (const float*)d_in[13];
    const float* W2           = (const float*)d_in[14];
    const float* b2           = (const float*)d_in[15];
    float* out = (float*)d_out;

    const int Nn = in_sizes[1];   // 100000
    const int Ee = in_sizes[2];   // 1600000
    const int nb = (Nn + 255) / 256;

    char* wsp = (char*)d_ws;
    size_t off = 0;
    auto alloc = [&](size_t bytes) -> void* {
        void* p = wsp + off;
        off = (off + bytes + 255) & ~(size_t)255;
        return p;
    };
    int* flag    = (int*)alloc(sizeof(int));
    int* bsums   = (int*)alloc((size_t)(nb + 1) * sizeof(int));
    int* mask01  = (int*)alloc((size_t)Nn * sizeof(int));
    int* order   = (int*)alloc((size_t)Nn * sizeof(int));
    int* inv     = (int*)alloc((size_t)Nn * sizeof(int));
    int* rowst   = (int*)alloc((size_t)(Nn + 1) * sizeof(int));
    u16* WqkvTh  = (u16*)alloc((size_t)576 * 192 * 2);
    u16* WqkvTl  = (u16*)alloc((size_t)576 * 192 * 2);
    u16* WoutTh  = (u16*)alloc((size_t)192 * 192 * 2);
    u16* WoutTl  = (u16*)alloc((size_t)192 * 192 * 2);
    u16* W1Th    = (u16*)alloc((size_t)384 * 192 * 2);
    u16* W1Tl    = (u16*)alloc((size_t)384 * 192 * 2);
    u16* W2Th    = (u16*)alloc((size_t)192 * 384 * 2);
    u16* W2Tl    = (u16*)alloc((size_t)192 * 384 * 2);
    // BufA hi/lo: ln1 -> agg -> hn
    u16* BufAh   = (u16*)alloc((size_t)Nn * D * 2);
    u16* BufAl   = (u16*)alloc((size_t)Nn * D * 2);
    // q,k,v single bf16 [Nn][192]; q+k reused as g1 bf16 [Nn][384]
    u16* qb      = (u16*)alloc((size_t)Nn * D * 2);
    u16* kb      = (u16*)alloc((size_t)Nn * D * 2);
    u16* vb      = (u16*)alloc((size_t)Nn * D * 2);
    float* score = (float*)alloc((size_t)Ee * 4 * sizeof(float));
    (void)ws_size; (void)n_in; (void)out_size;
    u16* g1b = qb;  // [Nn][384] overlays q+k (dead after node_attn)

    hipMemsetAsync(flag, 0, sizeof(int), stream);
    hipLaunchKernelGGL(detect_mask, dim3(nb), dim3(256), 0, stream, mraw, Nn, flag);
    hipLaunchKernelGGL(mask_convert, dim3(nb), dim3(256), 0, stream, mraw, flag, mask01, Nn);
    hipLaunchKernelGGL(scan_block_sums, dim3(nb), dim3(256), 0, stream, mask01, bsums, Nn);
    hipLaunchKernelGGL(scan_scan, dim3(1), dim3(512), 0, stream, bsums, nb);
    hipLaunchKernelGGL(make_order, dim3(nb), dim3(256), 0, stream, mask01, bsums, nb, order, inv, Nn);

    hipLaunchKernelGGL(wt_kern, dim3((192 * 576 + 255) / 256), dim3(256), 0, stream, Wqkv, WqkvTh, WqkvTl, 192, 576);
    hipLaunchKernelGGL(wt_kern, dim3((192 * 192 + 255) / 256), dim3(256), 0, stream, Wout, WoutTh, WoutTl, 192, 192);
    hipLaunchKernelGGL(wt_kern, dim3((192 * 384 + 255) / 256), dim3(256), 0, stream, W1, W1Th, W1Tl, 192, 384);
    hipLaunchKernelGGL(wt_kern, dim3((384 * 192 + 255) / 256), dim3(256), 0, stream, W2, W2Th, W2Tl, 384, 192);

    // ln1[p] = LN(x[order[p]]) (hi/lo)
    hipLaunchKernelGGL(gather_ln1, dim3((Nn + 3) / 4), dim3(256), 0, stream,
                       x, order, ln1_g, ln1_b, BufAh, BufAl, Nn);

    const int MB = (Nn + 63) / 64;
    // qkv = ln1 @ Wqkv + bqkv -> route to q/k/v (single bf16)
    hipLaunchKernelGGL((gemm_mfma<0, true>), dim3(MB, 9), dim3(256), 0, stream,
                       BufAh, BufAl, WqkvTh, WqkvTl, bqkv,
                       (float*)nullptr, (const float*)nullptr, (const int*)nullptr,
                       qb, kb, vb, (u16*)nullptr, Nn, 192, 576);

    hipLaunchKernelGGL(row_starts, dim3((Nn + 1 + 255) / 256), dim3(256), 0, stream, dst, rowst, Nn, Ee);
    hipLaunchKernelGGL(edge_scores, dim3((Ee + 3) / 4), dim3(256), 0, stream, kb, qb, src, dst, score, Ee);
    hipLaunchKernelGGL(node_attn, dim3((Nn + 3) / 4), dim3(256), 0, stream, vb, score, src, rowst, BufAh, BufAl, Nn);

    // out[order[p]] = x[order[p]] + (agg @ Wout + bout)[p]   (scatter with ORDER)
    hipLaunchKernelGGL((gemm_mfma<1, true>), dim3(MB, 3), dim3(256), 0, stream,
                       BufAh, BufAl, WoutTh, WoutTl, bout, out, x, order,
                       (u16*)nullptr, (u16*)nullptr, (u16*)nullptr, (u16*)nullptr, Nn, 192, 192);

    // hn = LN2(out) (hi/lo)
    hipLaunchKernelGGL(ln2_kern, dim3((Nn + 3) / 4), dim3(256), 0, stream, out, ln2_g, ln2_b, BufAh, BufAl, Nn);

    // g1 = gelu(hn @ W1 + b1) (single bf16)
    hipLaunchKernelGGL((gemm_mfma<2, true>), dim3(MB, 6), dim3(256), 0, stream,
                       BufAh, BufAl, W1Th, W1Tl, b1,
                       (float*)nullptr, (const float*)nullptr, (const int*)nullptr,
                       (u16*)nullptr, (u16*)nullptr, (u16*)nullptr, g1b, Nn, 192, 384);

    // out += g1 @ W2 + b2   (A single bf16)
    hipLaunchKernelGGL((gemm_mfma<3, false>), dim3(MB, 3), dim3(256), 0, stream,
                       g1b, (const u16*)nullptr, W2Th, W2Tl, b2, out,
                       (const float*)nullptr, (const int*)nullptr,
                       (u16*)nullptr, (u16*)nullptr, (u16*)nullptr, (u16*)nullptr, Nn, 384, 192);
}

// Round 7
// 792.653 us; speedup vs baseline: 2.0308x; 1.4092x over previous
//
#include <hip/hip_runtime.h>
#include <hip/hip_bf16.h>

constexpr int D   = 192;
constexpr float COEF = 0.14433756729740643f; // 1/sqrt(48)

typedef unsigned short u16;
typedef __bf16 bf16x8 __attribute__((ext_vector_type(8)));
typedef float  f32x4  __attribute__((ext_vector_type(4)));

__device__ __forceinline__ float gelu_f(float v) {
    return 0.5f * v * (1.0f + erff(v * 0.7071067811865475f));
}
__device__ __forceinline__ float bf2f(u16 u) {
    unsigned x = ((unsigned)u) << 16;
    union { unsigned u; float f; } c; c.u = x; return c.f;
}
__device__ __forceinline__ u16 f2bf(float f) {
    __hip_bfloat16 h = __float2bfloat16(f);
    union { __hip_bfloat16 h; u16 s; } c; c.h = h; return c.s;
}
// split f32 -> hi/lo bf16 pair (v ~= hi + lo)
__device__ __forceinline__ void splitbf(float v, u16& hi, u16& lo) {
    hi = f2bf(v);
    lo = f2bf(v - bf2f(hi));
}

// ---------------------------------------------------------------------------
// mask dtype detection: bool (1B) vs int32 (4B)
__global__ void detect_mask(const unsigned char* __restrict__ p, int nbytes, int* __restrict__ flag) {
    int i = blockIdx.x * blockDim.x + threadIdx.x;
    int v = 0;
    if (i < nbytes && (i & 3) != 0 && p[i] != 0) v = 1;
    unsigned long long bal = __ballot(v);
    if (bal && (threadIdx.x & 63) == 0) atomicOr(flag, 1);
}
__global__ void mask_convert(const unsigned char* __restrict__ raw, const int* __restrict__ flag,
                             int* __restrict__ mask01, int n) {
    int i = blockIdx.x * blockDim.x + threadIdx.x;
    if (i >= n) return;
    bool isBool = (flag[0] != 0);
    mask01[i] = isBool ? (raw[i] != 0) : (((const int*)raw)[i] != 0);
}

// ---------------------------------------------------------------------------
// prefix scan over mask to build order / inv (rank permutation + inverse)
__global__ void scan_block_sums(const int* __restrict__ m01, int* __restrict__ bsums, int n) {
    int i = blockIdx.x * 256 + threadIdx.x;
    int v = (i < n) ? m01[i] : 0;
    unsigned long long bal = __ballot(v != 0);
    __shared__ int wsum[4];
    int lane = threadIdx.x & 63, w = threadIdx.x >> 6;
    if (lane == 0) wsum[w] = __popcll(bal);
    __syncthreads();
    if (threadIdx.x == 0) bsums[blockIdx.x] = wsum[0] + wsum[1] + wsum[2] + wsum[3];
}
__global__ void scan_scan(int* __restrict__ bs, int nb) {
    __shared__ int s[512];
    int t = threadIdx.x;
    int v = (t < nb) ? bs[t] : 0;
    s[t] = v;
    __syncthreads();
    for (int off = 1; off < 512; off <<= 1) {
        int add = (t >= off) ? s[t - off] : 0;
        __syncthreads();
        s[t] += add;
        __syncthreads();
    }
    int incl = s[t];
    if (t < nb) bs[t] = incl - v;
    if (t == nb - 1) bs[nb] = incl;
}
__global__ void make_order(const int* __restrict__ m01, const int* __restrict__ bs, int nb,
                           int* __restrict__ order, int* __restrict__ inv, int n) {
    int i = blockIdx.x * 256 + threadIdx.x;
    int lane = threadIdx.x & 63, w = threadIdx.x >> 6;
    int m = (i < n) ? m01[i] : 0;
    unsigned long long bal = __ballot(m != 0);
    int lower = __popcll(bal & ((1ULL << lane) - 1ULL));
    __shared__ int wsum[4];
    if (lane == 0) wsum[w] = __popcll(bal);
    __syncthreads();
    int wpre = 0;
    for (int k = 0; k < w; ++k) wpre += wsum[k];
    if (i < n) {
        int cntT = bs[blockIdx.x] + wpre + lower;
        int T = bs[nb];
        int o = m ? cntT : (T + (i - cntT));  // rank(i)
        order[i] = o;
        inv[o] = i;
    }
}

// ---------------------------------------------------------------------------
// weight convert+transpose into hi/lo: Wt*[n*K+k] = split(W[k*N+n])
__global__ void wt_kern(const float* __restrict__ W, u16* __restrict__ Wth, u16* __restrict__ Wtl,
                        int K, int N) {
    int i = blockIdx.x * blockDim.x + threadIdx.x;
    if (i >= K * N) return;
    int k = i / N, n = i - k * N;
    u16 h, l;
    splitbf(W[i], h, l);
    Wth[(size_t)n * K + k] = h;
    Wtl[(size_t)n * K + k] = l;
}

// ---------------------------------------------------------------------------
// gather + LN1 -> bf16
__global__ __launch_bounds__(256) void gather_ln1(
    const float* __restrict__ x, const int* __restrict__ order,
    const float* __restrict__ g, const float* __restrict__ b,
    u16* __restrict__ lnH, int Nn)
{
    int w = threadIdx.x >> 6, lane = threadIdx.x & 63;
    int p = blockIdx.x * 4 + w;
    if (p >= Nn) return;
    const float* xr = x + (size_t)order[p] * D;
    int c = lane * 3;
    float v0 = xr[c], v1 = xr[c + 1], v2 = xr[c + 2];
    float s = v0 + v1 + v2;
    #pragma unroll
    for (int m = 32; m; m >>= 1) s += __shfl_xor(s, m);
    float mu = s * (1.0f / 192.0f);
    float d0 = v0 - mu, d1 = v1 - mu, d2 = v2 - mu;
    float q = d0 * d0 + d1 * d1 + d2 * d2;
    #pragma unroll
    for (int m = 32; m; m >>= 1) q += __shfl_xor(q, m);
    float r = rsqrtf(q * (1.0f / 192.0f) + 1e-5f);
    size_t base = (size_t)p * D + c;
    lnH[base]     = f2bf(d0 * r * g[c]     + b[c]);
    lnH[base + 1] = f2bf(d1 * r * g[c + 1] + b[c + 1]);
    lnH[base + 2] = f2bf(d2 * r * g[c + 2] + b[c + 2]);
}

// LN2: f32 in -> bf16 out
__global__ __launch_bounds__(256) void ln2_kern(
    const float* __restrict__ in, const float* __restrict__ g, const float* __restrict__ b,
    u16* __restrict__ outH, int Nn)
{
    int w = threadIdx.x >> 6, lane = threadIdx.x & 63;
    int p = blockIdx.x * 4 + w;
    if (p >= Nn) return;
    const float* xr = in + (size_t)p * D;
    int c = lane * 3;
    float v0 = xr[c], v1 = xr[c + 1], v2 = xr[c + 2];
    float s = v0 + v1 + v2;
    #pragma unroll
    for (int m = 32; m; m >>= 1) s += __shfl_xor(s, m);
    float mu = s * (1.0f / 192.0f);
    float d0 = v0 - mu, d1 = v1 - mu, d2 = v2 - mu;
    float q = d0 * d0 + d1 * d1 + d2 * d2;
    #pragma unroll
    for (int m = 32; m; m >>= 1) q += __shfl_xor(q, m);
    float r = rsqrtf(q * (1.0f / 192.0f) + 1e-5f);
    size_t base = (size_t)p * D + c;
    outH[base]     = f2bf(d0 * r * g[c]     + b[c]);
    outH[base + 1] = f2bf(d1 * r * g[c + 1] + b[c + 1]);
    outH[base + 2] = f2bf(d2 * r * g[c + 2] + b[c + 2]);
}

// ---------------------------------------------------------------------------
// MFMA GEMM: C = A[M,K] @ B[K,Nc] + bias. A single bf16; Bt hi+lo bf16 [Nc][K].
// A*B ~= A*Bh + A*Bl (B-side f32-grade; A-side one bf16 rounding).
// BM=BN=64, BK=32, 4 waves (2x2), each wave 2x2 frags of 16x16x32, 8 MFMA/step.
// EPI: 0 = route cols to q/k/v bf16 buffers (Nc=576)
//      1 = out[perm[row]] = x[perm[row]] + val   (scatter with ORDER)
//      2 = obf[row] = bf16(gelu(val))
//      3 = outF[row] += val                      (f32 RMW residual)
template<int EPI>
__global__ __launch_bounds__(256) void gemm_mfma(
    const u16* __restrict__ Ah,
    const u16* __restrict__ Bth, const u16* __restrict__ Btl,
    const float* __restrict__ bias,
    float* __restrict__ outF, const float* __restrict__ xres, const int* __restrict__ perm,
    u16* __restrict__ oq, u16* __restrict__ ok, u16* __restrict__ ov, u16* __restrict__ obf,
    int M, int K, int Nc)
{
    constexpr int LDT = 40;               // padded LDS row: only 2-way bank conflicts (free)
    __shared__ u16 AsH[64 * LDT];
    __shared__ u16 BsH[64 * LDT];
    __shared__ u16 BsL[64 * LDT];
    int tid = threadIdx.x;
    int lane = tid & 63, w = tid >> 6;
    int wr = w >> 1, wc = w & 1;
    int bm = blockIdx.x * 64, bn = blockIdx.y * 64;

    int srow = tid >> 2;                  // 0..63
    int scg  = (tid & 3) * 8;             // 0,8,16,24

    f32x4 acc[2][2];
    #pragma unroll
    for (int i = 0; i < 2; ++i)
        #pragma unroll
        for (int j = 0; j < 2; ++j)
            acc[i][j] = (f32x4){0.f, 0.f, 0.f, 0.f};

    for (int kk = 0; kk < K; kk += 32) {
        bool arow_ok = (bm + srow < M);
        size_t aoff = (size_t)(bm + srow) * K + kk + scg;
        uint4 avh = make_uint4(0, 0, 0, 0);
        if (arow_ok) avh = *(const uint4*)(Ah + aoff);
        *(uint4*)&AsH[srow * LDT + scg] = avh;
        size_t boff = (size_t)(bn + srow) * K + kk + scg;
        *(uint4*)&BsH[srow * LDT + scg] = *(const uint4*)(Bth + boff);
        *(uint4*)&BsL[srow * LDT + scg] = *(const uint4*)(Btl + boff);
        __syncthreads();

        int arow = (wr * 32 + (lane & 15)) * LDT + (lane >> 4) * 8;
        int brow = (wc * 32 + (lane & 15)) * LDT + (lane >> 4) * 8;
        bf16x8 a0h = *(const bf16x8*)&AsH[arow];
        bf16x8 a1h = *(const bf16x8*)&AsH[arow + 16 * LDT];
        bf16x8 b0h = *(const bf16x8*)&BsH[brow];
        bf16x8 b1h = *(const bf16x8*)&BsH[brow + 16 * LDT];
        bf16x8 b0l = *(const bf16x8*)&BsL[brow];
        bf16x8 b1l = *(const bf16x8*)&BsL[brow + 16 * LDT];
        acc[0][0] = __builtin_amdgcn_mfma_f32_16x16x32_bf16(a0h, b0h, acc[0][0], 0, 0, 0);
        acc[0][1] = __builtin_amdgcn_mfma_f32_16x16x32_bf16(a0h, b1h, acc[0][1], 0, 0, 0);
        acc[1][0] = __builtin_amdgcn_mfma_f32_16x16x32_bf16(a1h, b0h, acc[1][0], 0, 0, 0);
        acc[1][1] = __builtin_amdgcn_mfma_f32_16x16x32_bf16(a1h, b1h, acc[1][1], 0, 0, 0);
        acc[0][0] = __builtin_amdgcn_mfma_f32_16x16x32_bf16(a0h, b0l, acc[0][0], 0, 0, 0);
        acc[0][1] = __builtin_amdgcn_mfma_f32_16x16x32_bf16(a0h, b1l, acc[0][1], 0, 0, 0);
        acc[1][0] = __builtin_amdgcn_mfma_f32_16x16x32_bf16(a1h, b0l, acc[1][0], 0, 0, 0);
        acc[1][1] = __builtin_amdgcn_mfma_f32_16x16x32_bf16(a1h, b1l, acc[1][1], 0, 0, 0);
        __syncthreads();
    }

    // C/D layout: col = lane&15, row = (lane>>4)*4 + reg
    #pragma unroll
    for (int fm = 0; fm < 2; ++fm) {
        #pragma unroll
        for (int fn = 0; fn < 2; ++fn) {
            int col = bn + wc * 32 + fn * 16 + (lane & 15);
            float bcol = bias[col];
            #pragma unroll
            for (int r = 0; r < 4; ++r) {
                int row = bm + wr * 32 + fm * 16 + (lane >> 4) * 4 + r;
                if (row >= M) continue;
                float val = acc[fm][fn][r] + bcol;
                if (EPI == 0) {
                    int h = col / 144, rr = col - h * 144;
                    int sub = rr / 48, d = rr - sub * 48;
                    u16* dp = (sub == 0) ? oq : (sub == 1) ? ok : ov;
                    dp[(size_t)row * 192 + h * 48 + d] = f2bf(val);
                } else if (EPI == 1) {
                    int j = perm[row];                    // j = order[p]
                    size_t o = (size_t)j * Nc + col;
                    outF[o] = xres[o] + val;
                } else if (EPI == 2) {
                    obf[(size_t)row * Nc + col] = f2bf(gelu_f(val));
                } else {
                    size_t o = (size_t)row * Nc + col;
                    outF[o] += val;
                }
            }
        }
    }
}

// ---------------------------------------------------------------------------
// row_start[n] = lower_bound(dst, n)
__global__ void row_starts(const int* __restrict__ dst, int* __restrict__ rowst, int Nn, int Ee) {
    int n = blockIdx.x * blockDim.x + threadIdx.x;
    if (n > Nn) return;
    int lo = 0, hi = Ee;
    while (lo < hi) {
        int mid = (lo + hi) >> 1;
        if (dst[mid] < n) lo = mid + 1; else hi = mid;
    }
    rowst[n] = lo;
}

// ---------------------------------------------------------------------------
// per-edge scores: 4 edges per wave (16 lanes/edge).
// lane j in group: head = j>>2, quarter = j&3 -> 12 elems via 3x ushort4.
// k,q contiguous [N][192] bf16 (head*48+d).
__global__ __launch_bounds__(256) void edge_scores(
    const u16* __restrict__ kb, const u16* __restrict__ qb,
    const int* __restrict__ src, const int* __restrict__ dst,
    float* __restrict__ score, int Ee)
{
    int tid = threadIdx.x;
    int grp = tid >> 4;                 // 0..15 (edge slot in block)
    int j   = tid & 15;                 // lane in group
    long e = (long)blockIdx.x * 16 + grp;
    if (e >= Ee) return;
    int head = j >> 2, part = j & 3;
    int se = src[e], de = dst[e];
    int c = head * 48 + part * 12;
    const u16* kr = kb + (size_t)se * 192 + c;
    const u16* qr = qb + (size_t)de * 192 + c;
    float s = 0.f;
    #pragma unroll
    for (int i = 0; i < 3; ++i) {
        ushort4 kv = *(const ushort4*)(kr + i * 4);
        ushort4 qv = *(const ushort4*)(qr + i * 4);
        s += bf2f(kv.x) * bf2f(qv.x) + bf2f(kv.y) * bf2f(qv.y)
           + bf2f(kv.z) * bf2f(qv.z) + bf2f(kv.w) * bf2f(qv.w);
    }
    s += __shfl_xor(s, 1);
    s += __shfl_xor(s, 2);
    if (part == 0) score[(size_t)e * 4 + head] = s * COEF;
}

// ---------------------------------------------------------------------------
// per-node softmax + V aggregation: one wave per node, 4-way edge parallel.
// lane = eg*16 + t; lane t owns elems [12t,12t+12) => head = t>>2.
__global__ __launch_bounds__(256) void node_attn(
    const u16* __restrict__ vb, const float* __restrict__ score,
    const int* __restrict__ src, const int* __restrict__ rowst,
    u16* __restrict__ aggH, int Nn)
{
    int w = threadIdx.x >> 6, lane = threadIdx.x & 63;
    int n = blockIdx.x * 4 + w;
    if (n >= Nn) return;
    int r0 = rowst[n], r1 = rowst[n + 1];
    int eg = lane >> 4, t = lane & 15;
    int ht = t >> 2;

    float mx0 = -3.4e38f, mx1 = -3.4e38f, mx2 = -3.4e38f, mx3 = -3.4e38f;
    for (int e = r0 + lane; e < r1; e += 64) {
        float4 sc = *(const float4*)(score + (size_t)e * 4);
        mx0 = fmaxf(mx0, sc.x); mx1 = fmaxf(mx1, sc.y);
        mx2 = fmaxf(mx2, sc.z); mx3 = fmaxf(mx3, sc.w);
    }
    #pragma unroll
    for (int m = 32; m; m >>= 1) {
        mx0 = fmaxf(mx0, __shfl_xor(mx0, m));
        mx1 = fmaxf(mx1, __shfl_xor(mx1, m));
        mx2 = fmaxf(mx2, __shfl_xor(mx2, m));
        mx3 = fmaxf(mx3, __shfl_xor(mx3, m));
    }
    float sm0 = 0.f, sm1 = 0.f, sm2 = 0.f, sm3 = 0.f;
    for (int e = r0 + lane; e < r1; e += 64) {
        float4 sc = *(const float4*)(score + (size_t)e * 4);
        sm0 += expf(sc.x - mx0); sm1 += expf(sc.y - mx1);
        sm2 += expf(sc.z - mx2); sm3 += expf(sc.w - mx3);
    }
    #pragma unroll
    for (int m = 32; m; m >>= 1) {
        sm0 += __shfl_xor(sm0, m);
        sm1 += __shfl_xor(sm1, m);
        sm2 += __shfl_xor(sm2, m);
        sm3 += __shfl_xor(sm3, m);
    }
    float mh = (ht == 0) ? mx0 : (ht == 1) ? mx1 : (ht == 2) ? mx2 : mx3;
    float zh = (ht == 0) ? sm0 : (ht == 1) ? sm1 : (ht == 2) ? sm2 : sm3;
    float iz = (r1 > r0) ? (1.0f / zh) : 0.0f;

    float acc[12];
    #pragma unroll
    for (int i = 0; i < 12; ++i) acc[i] = 0.f;
    for (int e = r0 + eg; e < r1; e += 4) {
        float4 sc = *(const float4*)(score + (size_t)e * 4);
        float sh = (ht == 0) ? sc.x : (ht == 1) ? sc.y : (ht == 2) ? sc.z : sc.w;
        float p = expf(sh - mh) * iz;
        const u16* vr = vb + (size_t)src[e] * 192 + t * 12;
        ushort4 v0 = *(const ushort4*)(vr);
        ushort4 v1 = *(const ushort4*)(vr + 4);
        ushort4 v2 = *(const ushort4*)(vr + 8);
        acc[0] += p * bf2f(v0.x); acc[1]  += p * bf2f(v0.y);
        acc[2] += p * bf2f(v0.z); acc[3]  += p * bf2f(v0.w);
        acc[4] += p * bf2f(v1.x); acc[5]  += p * bf2f(v1.y);
        acc[6] += p * bf2f(v1.z); acc[7]  += p * bf2f(v1.w);
        acc[8] += p * bf2f(v2.x); acc[9]  += p * bf2f(v2.y);
        acc[10] += p * bf2f(v2.z); acc[11] += p * bf2f(v2.w);
    }
    #pragma unroll
    for (int i = 0; i < 12; ++i) {
        acc[i] += __shfl_xor(acc[i], 16);
        acc[i] += __shfl_xor(acc[i], 32);
    }
    if (eg == 0) {
        size_t base = (size_t)n * 192 + t * 12;
        #pragma unroll
        for (int i = 0; i < 12; ++i) aggH[base + i] = f2bf(acc[i]);
    }
}

// ---------------------------------------------------------------------------
extern "C" void kernel_launch(void* const* d_in, const int* in_sizes, int n_in,
                              void* d_out, int out_size, void* d_ws, size_t ws_size,
                              hipStream_t stream)
{
    const float* x            = (const float*)d_in[0];
    const unsigned char* mraw = (const unsigned char*)d_in[1];
    const int* src            = (const int*)d_in[2];
    const int* dst            = (const int*)d_in[3];
    const float* ln1_g        = (const float*)d_in[4];
    const float* ln1_b        = (const float*)d_in[5];
    const float* Wqkv         = (const float*)d_in[6];
    const float* bqkv         = (const float*)d_in[7];
    const float* Wout         = (const float*)d_in[8];
    const float* bout         = (const float*)d_in[9];
    const float* ln2_g        = (const float*)d_in[10];
    const float* ln2_b        = (const float*)d_in[11];
    const float* W1           = (const float*)d_in[12];
    const float* b1           = (const float*)d_in[13];
    const float* W2           = (const float*)d_in[14];
    const float* b2           = (const float*)d_in[15];
    float* out = (float*)d_out;

    const int Nn = in_sizes[1];   // 100000
    const int Ee = in_sizes[2];   // 1600000
    const int nb = (Nn + 255) / 256;

    char* wsp = (char*)d_ws;
    size_t off = 0;
    auto alloc = [&](size_t bytes) -> void* {
        void* p = wsp + off;
        off = (off + bytes + 255) & ~(size_t)255;
        return p;
    };
    int* flag    = (int*)alloc(sizeof(int));
    int* bsums   = (int*)alloc((size_t)(nb + 1) * sizeof(int));
    int* mask01  = (int*)alloc((size_t)Nn * sizeof(int));
    int* order   = (int*)alloc((size_t)Nn * sizeof(int));
    int* inv     = (int*)alloc((size_t)Nn * sizeof(int));
    int* rowst   = (int*)alloc((size_t)(Nn + 1) * sizeof(int));
    u16* WqkvTh  = (u16*)alloc((size_t)576 * 192 * 2);
    u16* WqkvTl  = (u16*)alloc((size_t)576 * 192 * 2);
    u16* WoutTh  = (u16*)alloc((size_t)192 * 192 * 2);
    u16* WoutTl  = (u16*)alloc((size_t)192 * 192 * 2);
    u16* W1Th    = (u16*)alloc((size_t)384 * 192 * 2);
    u16* W1Tl    = (u16*)alloc((size_t)384 * 192 * 2);
    u16* W2Th    = (u16*)alloc((size_t)192 * 384 * 2);
    u16* W2Tl    = (u16*)alloc((size_t)192 * 384 * 2);
    // BufA bf16: ln1 -> agg -> hn
    u16* BufAh   = (u16*)alloc((size_t)Nn * D * 2);
    // q,k,v single bf16 [Nn][192]; q+k reused as g1 bf16 [Nn][384]
    u16* qb      = (u16*)alloc((size_t)Nn * D * 2);
    u16* kb      = (u16*)alloc((size_t)Nn * D * 2);
    u16* vb      = (u16*)alloc((size_t)Nn * D * 2);
    float* score = (float*)alloc((size_t)Ee * 4 * sizeof(float));
    (void)ws_size; (void)n_in; (void)out_size;
    u16* g1b = qb;  // [Nn][384] overlays q+k (dead after node_attn)

    hipMemsetAsync(flag, 0, sizeof(int), stream);
    hipLaunchKernelGGL(detect_mask, dim3(nb), dim3(256), 0, stream, mraw, Nn, flag);
    hipLaunchKernelGGL(mask_convert, dim3(nb), dim3(256), 0, stream, mraw, flag, mask01, Nn);
    hipLaunchKernelGGL(scan_block_sums, dim3(nb), dim3(256), 0, stream, mask01, bsums, Nn);
    hipLaunchKernelGGL(scan_scan, dim3(1), dim3(512), 0, stream, bsums, nb);
    hipLaunchKernelGGL(make_order, dim3(nb), dim3(256), 0, stream, mask01, bsums, nb, order, inv, Nn);

    hipLaunchKernelGGL(wt_kern, dim3((192 * 576 + 255) / 256), dim3(256), 0, stream, Wqkv, WqkvTh, WqkvTl, 192, 576);
    hipLaunchKernelGGL(wt_kern, dim3((192 * 192 + 255) / 256), dim3(256), 0, stream, Wout, WoutTh, WoutTl, 192, 192);
    hipLaunchKernelGGL(wt_kern, dim3((192 * 384 + 255) / 256), dim3(256), 0, stream, W1, W1Th, W1Tl, 192, 384);
    hipLaunchKernelGGL(wt_kern, dim3((384 * 192 + 255) / 256), dim3(256), 0, stream, W2, W2Th, W2Tl, 384, 192);

    // ln1[p] = LN(x[order[p]]) (bf16)
    hipLaunchKernelGGL(gather_ln1, dim3((Nn + 3) / 4), dim3(256), 0, stream,
                       x, order, ln1_g, ln1_b, BufAh, Nn);

    const int MB = (Nn + 63) / 64;
    // qkv = ln1 @ Wqkv + bqkv -> route to q/k/v
    hipLaunchKernelGGL((gemm_mfma<0>), dim3(MB, 9), dim3(256), 0, stream,
                       BufAh, WqkvTh, WqkvTl, bqkv,
                       (float*)nullptr, (const float*)nullptr, (const int*)nullptr,
                       qb, kb, vb, (u16*)nullptr, Nn, 192, 576);

    hipLaunchKernelGGL(row_starts, dim3((Nn + 1 + 255) / 256), dim3(256), 0, stream, dst, rowst, Nn, Ee);
    hipLaunchKernelGGL(edge_scores, dim3((unsigned)((Ee + 15) / 16)), dim3(256), 0, stream,
                       kb, qb, src, dst, score, Ee);
    hipLaunchKernelGGL(node_attn, dim3((Nn + 3) / 4), dim3(256), 0, stream, vb, score, src, rowst, BufAh, Nn);

    // out[order[p]] = x[order[p]] + (agg @ Wout + bout)[p]   (scatter with ORDER)
    hipLaunchKernelGGL((gemm_mfma<1>), dim3(MB, 3), dim3(256), 0, stream,
                       BufAh, WoutTh, WoutTl, bout, out, x, order,
                       (u16*)nullptr, (u16*)nullptr, (u16*)nullptr, (u16*)nullptr, Nn, 192, 192);

    // hn = LN2(out) (bf16)
    hipLaunchKernelGGL(ln2_kern, dim3((Nn + 3) / 4), dim3(256), 0, stream, out, ln2_g, ln2_b, BufAh, Nn);

    // g1 = gelu(hn @ W1 + b1) (bf16)
    hipLaunchKernelGGL((gemm_mfma<2>), dim3(MB, 6), dim3(256), 0, stream,
                       BufAh, W1Th, W1Tl, b1,
                       (float*)nullptr, (const float*)nullptr, (const int*)nullptr,
                       (u16*)nullptr, (u16*)nullptr, (u16*)nullptr, g1b, Nn, 192, 384);

    // out += g1 @ W2 + b2
    hipLaunchKernelGGL((gemm_mfma<3>), dim3(MB, 3), dim3(256), 0, stream,
                       g1b, W2Th, W2Tl, b2, out,
                       (const float*)nullptr, (const int*)nullptr,
                       (u16*)nullptr, (u16*)nullptr, (u16*)nullptr, (u16*)nullptr, Nn, 384, 192);
}